// Round 1
// baseline (274.536 us; speedup 1.0000x reference)
//
#include <hip/hip_runtime.h>

#define SEQ 4096
#define KDIM 1024
#define NQKV 3072

typedef __bf16 bf16x8 __attribute__((ext_vector_type(8)));
typedef float  f32x4  __attribute__((ext_vector_type(4)));

__device__ __forceinline__ unsigned short f2b(float f) {
    unsigned int u = __float_as_uint(f);
    u += 0x7FFFu + ((u >> 16) & 1u);   // round-to-nearest-even
    return (unsigned short)(u >> 16);
}
__device__ __forceinline__ float b2f(unsigned short h) {
    return __uint_as_float(((unsigned int)h) << 16);
}

__device__ __forceinline__ void gld_lds16(const unsigned short* g, unsigned short* l) {
    __builtin_amdgcn_global_load_lds(
        (const __attribute__((address_space(1))) void*)g,
        (__attribute__((address_space(3))) void*)l, 16, 0, 0);
}

// ---------------------------------------------------------------------------
// Core: 128x128 tile, BK=32, 4 waves (2x2), each wave 64x64 = 4x4 MFMA tiles.
// A operand: Ag[m][k] row-major (already offset to m0), lda elements/row.
// B operand: Bg[n][k] n-major    (already offset to n0), ldb elements/row.
// ---------------------------------------------------------------------------
__device__ __forceinline__ void mfma_tile_loop(
    const unsigned short* Ag, int lda,
    const unsigned short* Bg, int ldb,
    int kEnd, unsigned short* sA, unsigned short* sB, f32x4 acc[4][4])
{
    const int tid  = threadIdx.x;
    const int wave = tid >> 6, lane = tid & 63;
    const int lr   = lane & 15, quad = lane >> 4;
    const int wm   = (wave >> 1) * 64, wn = (wave & 1) * 64;

    #pragma unroll 1
    for (int k0 = 0; k0 < kEnd; k0 += 32) {
        // stage 128x32 bf16 tiles: 8 KiB each, 8 wave-calls of 1 KiB
        #pragma unroll
        for (int i = 0; i < 2; ++i) {
            int c = wave * 128 + i * 64 + lane;     // chunk id 0..511
            int row = c >> 2, piece = c & 3;        // 4 x 16B chunks per row
            unsigned short* dst = (unsigned short*)((wave * 2 + i) * 512);
            gld_lds16(Ag + row * lda + k0 + piece * 8, sA + (wave * 2 + i) * 512);
            gld_lds16(Bg + row * ldb + k0 + piece * 8, sB + (wave * 2 + i) * 512);
            (void)dst;
        }
        __syncthreads();
        bf16x8 af[4], bq[4];
        #pragma unroll
        for (int i = 0; i < 4; ++i)
            af[i] = *(const bf16x8*)(sA + (wm + 16 * i + lr) * 32 + quad * 8);
        #pragma unroll
        for (int j = 0; j < 4; ++j)
            bq[j] = *(const bf16x8*)(sB + (wn + 16 * j + lr) * 32 + quad * 8);
        #pragma unroll
        for (int i = 0; i < 4; ++i)
            #pragma unroll
            for (int j = 0; j < 4; ++j)
                acc[i][j] = __builtin_amdgcn_mfma_f32_16x16x32_bf16(af[i], bq[j], acc[i][j], 0, 0, 0);
        __syncthreads();
    }
}

__device__ __forceinline__ void zero_acc(f32x4 acc[4][4]) {
    const f32x4 z = {0.f, 0.f, 0.f, 0.f};
    #pragma unroll
    for (int i = 0; i < 4; ++i)
        #pragma unroll
        for (int j = 0; j < 4; ++j) acc[i][j] = z;
}

// ---------------------------------------------------------------------------
// Kernel 0a: x fp32 -> bf16
// ---------------------------------------------------------------------------
__global__ __launch_bounds__(256) void convert_x(const float* __restrict__ x,
                                                 unsigned short* __restrict__ Xb) {
    int i = (blockIdx.x * 256 + threadIdx.x) * 4;
    float4 v = *(const float4*)(x + i);
    ushort4 o;
    o.x = f2b(v.x); o.y = f2b(v.y); o.z = f2b(v.z); o.w = f2b(v.w);
    *(ushort4*)(Xb + i) = o;
}

// ---------------------------------------------------------------------------
// Kernel 0b: W [K][N] fp32 -> Wt [N][K] bf16 (tiled transpose)
// ---------------------------------------------------------------------------
__global__ __launch_bounds__(256) void transpose_W(const float* __restrict__ W,
                                                   unsigned short* __restrict__ Wt) {
    __shared__ float tile[32][33];
    const int n0 = blockIdx.x * 32;     // 0..3071
    const int k0 = blockIdx.y * 32;     // 0..1023
    const int c = threadIdx.x & 31;
    const int r0 = threadIdx.x >> 5;    // 0..7
    #pragma unroll
    for (int r = r0; r < 32; r += 8)
        tile[r][c] = W[(k0 + r) * NQKV + n0 + c];
    __syncthreads();
    #pragma unroll
    for (int r = r0; r < 32; r += 8)
        Wt[(n0 + r) * KDIM + k0 + c] = f2b(tile[c][r]);
}

// ---------------------------------------------------------------------------
// Kernel 1: qvk = Xb @ Wt^T  -> Q row-major, K row-major, V transposed (Vt[d][s])
// ---------------------------------------------------------------------------
__global__ __launch_bounds__(256) void qvk_gemm(
    const unsigned short* __restrict__ Xb, const unsigned short* __restrict__ Wt,
    unsigned short* __restrict__ Qb, unsigned short* __restrict__ Kb,
    unsigned short* __restrict__ Vt)
{
    __shared__ __align__(16) unsigned short sA[128 * 32];
    __shared__ __align__(16) unsigned short sB[128 * 32];
    const int m0 = blockIdx.y * 128;
    const int n0 = blockIdx.x * 128;    // 0..2944
    f32x4 acc[4][4];
    zero_acc(acc);
    mfma_tile_loop(Xb + m0 * KDIM, KDIM, Wt + n0 * KDIM, KDIM, KDIM, sA, sB, acc);

    const int lane = threadIdx.x & 63, wave = threadIdx.x >> 6;
    const int lr = lane & 15, quad = lane >> 4;
    const int wm = (wave >> 1) * 64, wn = (wave & 1) * 64;
    const int region = n0 >> 10;        // 0=Q, 1=V, 2=K (whole block in one region)
    const int nloc = n0 & 1023;
    #pragma unroll
    for (int i = 0; i < 4; ++i) {
        const int rbase = m0 + wm + 16 * i + quad * 4;
        #pragma unroll
        for (int j = 0; j < 4; ++j) {
            const int col = nloc + wn + 16 * j + lr;
            if (region == 0) {
                #pragma unroll
                for (int r = 0; r < 4; ++r)
                    Qb[(rbase + r) * KDIM + col] = f2b(acc[i][j][r]);
            } else if (region == 2) {
                #pragma unroll
                for (int r = 0; r < 4; ++r)
                    Kb[(rbase + r) * KDIM + col] = f2b(acc[i][j][r]);
            } else {
                ushort4 v;
                v.x = f2b(acc[i][j][0]); v.y = f2b(acc[i][j][1]);
                v.z = f2b(acc[i][j][2]); v.w = f2b(acc[i][j][3]);
                *(ushort4*)(Vt + col * SEQ + rbase) = v;   // Vt[d][s]
            }
        }
    }
}

// ---------------------------------------------------------------------------
// Kernel 2: S = (Q @ K^T) / 32, causal. Lower-triangular blocks only.
// ---------------------------------------------------------------------------
__global__ __launch_bounds__(256) void score_gemm(
    const unsigned short* __restrict__ Qb, const unsigned short* __restrict__ Kb,
    unsigned short* __restrict__ Sb)
{
    __shared__ __align__(16) unsigned short sA[128 * 32];
    __shared__ __align__(16) unsigned short sB[128 * 32];
    const int b = blockIdx.x;           // 0..527 -> (bm, bn), bn <= bm
    int bm = (int)((sqrtf(8.f * (float)b + 1.f) - 1.f) * 0.5f);
    while ((bm + 1) * (bm + 2) / 2 <= b) ++bm;
    while (bm * (bm + 1) / 2 > b) --bm;
    const int bn = b - bm * (bm + 1) / 2;
    const int m0 = bm * 128, n0 = bn * 128;

    f32x4 acc[4][4];
    zero_acc(acc);
    mfma_tile_loop(Qb + m0 * KDIM, KDIM, Kb + n0 * KDIM, KDIM, KDIM, sA, sB, acc);

    const int lane = threadIdx.x & 63, wave = threadIdx.x >> 6;
    const int lr = lane & 15, quad = lane >> 4;
    const int wm = (wave >> 1) * 64, wn = (wave & 1) * 64;
    #pragma unroll
    for (int i = 0; i < 4; ++i) {
        const int rbase = m0 + wm + 16 * i + quad * 4;
        #pragma unroll
        for (int j = 0; j < 4; ++j) {
            const int col = n0 + wn + 16 * j + lr;
            #pragma unroll
            for (int r = 0; r < 4; ++r) {
                const int row = rbase + r;
                float v = acc[i][j][r] * 0.03125f;
                if (col > row) v = -1e30f;            // causal mask (diag blocks)
                Sb[row * SEQ + col] = f2b(v);
            }
        }
    }
}

// ---------------------------------------------------------------------------
// Kernel 3: row softmax in-place on Sb (bf16). One block per row.
// Processes j in [0, 128-aligned end); masked entries (-1e30) -> exp = 0.
// ---------------------------------------------------------------------------
__global__ __launch_bounds__(256) void softmax_rows(unsigned short* __restrict__ Sb) {
    const int m = blockIdx.x;
    const int jend = ((m >> 7) + 1) << 7;
    const int tid = threadIdx.x;
    __shared__ float vals[SEQ];
    __shared__ float red[256];

    float lmax = -3.0e38f;
    for (int j = tid; j < jend; j += 256) {
        float x = b2f(Sb[m * SEQ + j]);
        vals[j] = x;
        lmax = fmaxf(lmax, x);
    }
    red[tid] = lmax;
    __syncthreads();
    for (int s = 128; s > 0; s >>= 1) {
        if (tid < s) red[tid] = fmaxf(red[tid], red[tid + s]);
        __syncthreads();
    }
    const float rmax = red[0];
    __syncthreads();

    float lsum = 0.f;
    for (int j = tid; j < jend; j += 256) {
        float e = expf(vals[j] - rmax);
        vals[j] = e;
        lsum += e;
    }
    red[tid] = lsum;
    __syncthreads();
    for (int s = 128; s > 0; s >>= 1) {
        if (tid < s) red[tid] += red[tid + s];
        __syncthreads();
    }
    const float inv = 1.0f / red[0];
    for (int j = tid; j < jend; j += 256)
        Sb[m * SEQ + j] = f2b(vals[j] * inv);
}

// ---------------------------------------------------------------------------
// Kernel 4: out = P @ V  (P = Sb bf16 row-major, V via Vt[d][s] n-major)
// Block-causal k-loop: k < (bm+1)*128.
// ---------------------------------------------------------------------------
__global__ __launch_bounds__(256) void pv_gemm(
    const unsigned short* __restrict__ Sb, const unsigned short* __restrict__ Vt,
    float* __restrict__ out)
{
    __shared__ __align__(16) unsigned short sA[128 * 32];
    __shared__ __align__(16) unsigned short sB[128 * 32];
    const int m0 = blockIdx.y * 128;
    const int n0 = blockIdx.x * 128;    // 0..896
    const int kend = m0 + 128;

    f32x4 acc[4][4];
    zero_acc(acc);
    mfma_tile_loop(Sb + m0 * SEQ, SEQ, Vt + n0 * SEQ, SEQ, kend, sA, sB, acc);

    const int lane = threadIdx.x & 63, wave = threadIdx.x >> 6;
    const int lr = lane & 15, quad = lane >> 4;
    const int wm = (wave >> 1) * 64, wn = (wave & 1) * 64;
    #pragma unroll
    for (int i = 0; i < 4; ++i) {
        const int rbase = m0 + wm + 16 * i + quad * 4;
        #pragma unroll
        for (int j = 0; j < 4; ++j) {
            const int col = n0 + wn + 16 * j + lr;
            #pragma unroll
            for (int r = 0; r < 4; ++r)
                out[(rbase + r) * KDIM + col] = acc[i][j][r];
        }
    }
}

// ---------------------------------------------------------------------------
extern "C" void kernel_launch(void* const* d_in, const int* in_sizes, int n_in,
                              void* d_out, int out_size, void* d_ws, size_t ws_size,
                              hipStream_t stream) {
    const float* x = (const float*)d_in[0];   // [4096][1024]
    const float* W = (const float*)d_in[1];   // [1024][3072]
    float* out = (float*)d_out;               // [4096][1024]
    char* ws = (char*)d_ws;

    // workspace layout (bytes)
    unsigned short* Xb = (unsigned short*)(ws);                     //  8 MiB
    unsigned short* Wt = (unsigned short*)(ws + 8388608);           //  6 MiB
    unsigned short* Qb = (unsigned short*)(ws + 14680064);          //  8 MiB
    unsigned short* Kb = (unsigned short*)(ws + 23068672);          //  8 MiB
    unsigned short* Vt = (unsigned short*)(ws + 31457280);          //  8 MiB
    unsigned short* Sb = (unsigned short*)(ws + 39845888);          // 32 MiB  (ends 73400320)

    convert_x  <<<SEQ * KDIM / (256 * 4), 256, 0, stream>>>(x, Xb);
    transpose_W<<<dim3(NQKV / 32, KDIM / 32), 256, 0, stream>>>(W, Wt);
    qvk_gemm   <<<dim3(NQKV / 128, SEQ / 128), 256, 0, stream>>>(Xb, Wt, Qb, Kb, Vt);
    score_gemm <<<(SEQ / 128) * (SEQ / 128 + 1) / 2, 256, 0, stream>>>(Qb, Kb, Sb);
    softmax_rows<<<SEQ, 256, 0, stream>>>(Sb);
    pv_gemm    <<<dim3(KDIM / 128, SEQ / 128), 256, 0, stream>>>(Sb, Vt, out);
}

// Round 2
// 244.480 us; speedup vs baseline: 1.1229x; 1.1229x over previous
//
#include <hip/hip_runtime.h>

#define SEQ 4096
#define KDIM 1024
#define NQKV 3072

typedef __bf16 bf16x8 __attribute__((ext_vector_type(8)));
typedef float  f32x4  __attribute__((ext_vector_type(4)));

__device__ __forceinline__ unsigned short f2b(float f) {
    unsigned int u = __float_as_uint(f);
    u += 0x7FFFu + ((u >> 16) & 1u);   // round-to-nearest-even
    return (unsigned short)(u >> 16);
}
__device__ __forceinline__ float b2f(unsigned short h) {
    return __uint_as_float(((unsigned int)h) << 16);
}

__device__ __forceinline__ void gld_lds16(const unsigned short* g, unsigned short* l) {
    __builtin_amdgcn_global_load_lds(
        (const __attribute__((address_space(1))) void*)g,
        (__attribute__((address_space(3))) void*)l, 16, 0, 0);
}

// ---------------------------------------------------------------------------
// Core: 128x128 tile, BK=32, 4 waves (2x2), each wave 64x64 = 4x4 MFMA tiles.
// A operand: Ag[m][k] row-major (already offset to m0/kstart), lda elems/row.
// B operand: Bg[n][k] n-major    (already offset to n0/kstart), ldb elems/row.
// ---------------------------------------------------------------------------
__device__ __forceinline__ void mfma_tile_loop(
    const unsigned short* Ag, int lda,
    const unsigned short* Bg, int ldb,
    int kLen, unsigned short* sA, unsigned short* sB, f32x4 acc[4][4])
{
    const int tid  = threadIdx.x;
    const int wave = tid >> 6, lane = tid & 63;
    const int lr   = lane & 15, quad = lane >> 4;
    const int wm   = (wave >> 1) * 64, wn = (wave & 1) * 64;

    #pragma unroll 1
    for (int k0 = 0; k0 < kLen; k0 += 32) {
        // stage 128x32 bf16 tiles: 8 KiB each, 8 wave-calls of 1 KiB
        #pragma unroll
        for (int i = 0; i < 2; ++i) {
            int c = wave * 128 + i * 64 + lane;     // chunk id 0..511
            int row = c >> 2, piece = c & 3;        // 4 x 16B chunks per row
            gld_lds16(Ag + row * lda + k0 + piece * 8, sA + (wave * 2 + i) * 512);
            gld_lds16(Bg + row * ldb + k0 + piece * 8, sB + (wave * 2 + i) * 512);
        }
        __syncthreads();
        bf16x8 af[4], bq[4];
        #pragma unroll
        for (int i = 0; i < 4; ++i)
            af[i] = *(const bf16x8*)(sA + (wm + 16 * i + lr) * 32 + quad * 8);
        #pragma unroll
        for (int j = 0; j < 4; ++j)
            bq[j] = *(const bf16x8*)(sB + (wn + 16 * j + lr) * 32 + quad * 8);
        #pragma unroll
        for (int i = 0; i < 4; ++i)
            #pragma unroll
            for (int j = 0; j < 4; ++j)
                acc[i][j] = __builtin_amdgcn_mfma_f32_16x16x32_bf16(af[i], bq[j], acc[i][j], 0, 0, 0);
        __syncthreads();
    }
}

__device__ __forceinline__ void zero_acc(f32x4 acc[4][4]) {
    const f32x4 z = {0.f, 0.f, 0.f, 0.f};
    #pragma unroll
    for (int i = 0; i < 4; ++i)
        #pragma unroll
        for (int j = 0; j < 4; ++j) acc[i][j] = z;
}

// ---------------------------------------------------------------------------
// Kernel 0a: x fp32 -> bf16
// ---------------------------------------------------------------------------
__global__ __launch_bounds__(256) void convert_x(const float* __restrict__ x,
                                                 unsigned short* __restrict__ Xb) {
    int i = (blockIdx.x * 256 + threadIdx.x) * 4;
    float4 v = *(const float4*)(x + i);
    ushort4 o;
    o.x = f2b(v.x); o.y = f2b(v.y); o.z = f2b(v.z); o.w = f2b(v.w);
    *(ushort4*)(Xb + i) = o;
}

// ---------------------------------------------------------------------------
// Kernel 0b: W [K][N] fp32 -> Wt [N][K] bf16 (tiled transpose)
// ---------------------------------------------------------------------------
__global__ __launch_bounds__(256) void transpose_W(const float* __restrict__ W,
                                                   unsigned short* __restrict__ Wt) {
    __shared__ float tile[32][33];
    const int n0 = blockIdx.x * 32;     // 0..3071
    const int k0 = blockIdx.y * 32;     // 0..1023
    const int c = threadIdx.x & 31;
    const int r0 = threadIdx.x >> 5;    // 0..7
    #pragma unroll
    for (int r = r0; r < 32; r += 8)
        tile[r][c] = W[(k0 + r) * NQKV + n0 + c];
    __syncthreads();
    #pragma unroll
    for (int r = r0; r < 32; r += 8)
        Wt[(n0 + r) * KDIM + k0 + c] = f2b(tile[c][r]);
}

// ---------------------------------------------------------------------------
// Kernel 0c: zero d_out (harness poisons it with 0xAA; pv accumulates)
// ---------------------------------------------------------------------------
__global__ __launch_bounds__(256) void zero_out(float4* __restrict__ out) {
    const float4 z = {0.f, 0.f, 0.f, 0.f};
    out[blockIdx.x * 256 + threadIdx.x] = z;
}

// ---------------------------------------------------------------------------
// Kernel 1: qvk = Xb @ Wt^T  -> Q row-major, K row-major, V transposed (Vt[d][s])
// ---------------------------------------------------------------------------
__global__ __launch_bounds__(256) void qvk_gemm(
    const unsigned short* __restrict__ Xb, const unsigned short* __restrict__ Wt,
    unsigned short* __restrict__ Qb, unsigned short* __restrict__ Kb,
    unsigned short* __restrict__ Vt)
{
    __shared__ __align__(16) unsigned short sA[128 * 32];
    __shared__ __align__(16) unsigned short sB[128 * 32];
    const int m0 = blockIdx.y * 128;
    const int n0 = blockIdx.x * 128;    // 0..2944
    f32x4 acc[4][4];
    zero_acc(acc);
    mfma_tile_loop(Xb + m0 * KDIM, KDIM, Wt + n0 * KDIM, KDIM, KDIM, sA, sB, acc);

    const int lane = threadIdx.x & 63, wave = threadIdx.x >> 6;
    const int lr = lane & 15, quad = lane >> 4;
    const int wm = (wave >> 1) * 64, wn = (wave & 1) * 64;
    const int region = n0 >> 10;        // 0=Q, 1=V, 2=K (whole block in one region)
    const int nloc = n0 & 1023;
    #pragma unroll
    for (int i = 0; i < 4; ++i) {
        const int rbase = m0 + wm + 16 * i + quad * 4;
        #pragma unroll
        for (int j = 0; j < 4; ++j) {
            const int col = nloc + wn + 16 * j + lr;
            if (region == 0) {
                #pragma unroll
                for (int r = 0; r < 4; ++r)
                    Qb[(rbase + r) * KDIM + col] = f2b(acc[i][j][r]);
            } else if (region == 2) {
                #pragma unroll
                for (int r = 0; r < 4; ++r)
                    Kb[(rbase + r) * KDIM + col] = f2b(acc[i][j][r]);
            } else {
                ushort4 v;
                v.x = f2b(acc[i][j][0]); v.y = f2b(acc[i][j][1]);
                v.z = f2b(acc[i][j][2]); v.w = f2b(acc[i][j][3]);
                *(ushort4*)(Vt + col * SEQ + rbase) = v;   // Vt[d][s]
            }
        }
    }
}

// ---------------------------------------------------------------------------
// Kernel 2: S = (Q @ K^T) / 32, causal. Lower-triangular blocks only.
// ---------------------------------------------------------------------------
__global__ __launch_bounds__(256) void score_gemm(
    const unsigned short* __restrict__ Qb, const unsigned short* __restrict__ Kb,
    unsigned short* __restrict__ Sb)
{
    __shared__ __align__(16) unsigned short sA[128 * 32];
    __shared__ __align__(16) unsigned short sB[128 * 32];
    const int b = blockIdx.x;           // 0..527 -> (bm, bn), bn <= bm
    int bm = (int)((sqrtf(8.f * (float)b + 1.f) - 1.f) * 0.5f);
    while ((bm + 1) * (bm + 2) / 2 <= b) ++bm;
    while (bm * (bm + 1) / 2 > b) --bm;
    const int bn = b - bm * (bm + 1) / 2;
    const int m0 = bm * 128, n0 = bn * 128;

    f32x4 acc[4][4];
    zero_acc(acc);
    mfma_tile_loop(Qb + m0 * KDIM, KDIM, Kb + n0 * KDIM, KDIM, KDIM, sA, sB, acc);

    const int lane = threadIdx.x & 63, wave = threadIdx.x >> 6;
    const int lr = lane & 15, quad = lane >> 4;
    const int wm = (wave >> 1) * 64, wn = (wave & 1) * 64;
    #pragma unroll
    for (int i = 0; i < 4; ++i) {
        const int rbase = m0 + wm + 16 * i + quad * 4;
        #pragma unroll
        for (int j = 0; j < 4; ++j) {
            const int col = n0 + wn + 16 * j + lr;
            #pragma unroll
            for (int r = 0; r < 4; ++r) {
                const int row = rbase + r;
                float v = acc[i][j][r] * 0.03125f;
                if (col > row) v = -1e30f;            // causal mask (diag blocks)
                Sb[row * SEQ + col] = f2b(v);
            }
        }
    }
}

// ---------------------------------------------------------------------------
// Kernel 3: row softmax in-place on Sb (bf16). One block per row.
// Processes j in [0, 128-aligned end); masked entries (-1e30) -> exp = 0.
// ---------------------------------------------------------------------------
__global__ __launch_bounds__(256) void softmax_rows(unsigned short* __restrict__ Sb) {
    const int m = blockIdx.x;
    const int jend = ((m >> 7) + 1) << 7;
    const int tid = threadIdx.x;
    __shared__ float vals[SEQ];
    __shared__ float red[256];

    float lmax = -3.0e38f;
    for (int j = tid; j < jend; j += 256) {
        float x = b2f(Sb[m * SEQ + j]);
        vals[j] = x;
        lmax = fmaxf(lmax, x);
    }
    red[tid] = lmax;
    __syncthreads();
    for (int s = 128; s > 0; s >>= 1) {
        if (tid < s) red[tid] = fmaxf(red[tid], red[tid + s]);
        __syncthreads();
    }
    const float rmax = red[0];
    __syncthreads();

    float lsum = 0.f;
    for (int j = tid; j < jend; j += 256) {
        float e = expf(vals[j] - rmax);
        vals[j] = e;
        lsum += e;
    }
    red[tid] = lsum;
    __syncthreads();
    for (int s = 128; s > 0; s >>= 1) {
        if (tid < s) red[tid] += red[tid + s];
        __syncthreads();
    }
    const float inv = 1.0f / red[0];
    for (int j = tid; j < jend; j += 256)
        Sb[m * SEQ + j] = f2b(vals[j] * inv);
}

// ---------------------------------------------------------------------------
// Kernel 4: out = P @ V, split-K over the causal K-extent.
// blockIdx.y -> (m-tile, k-chunk) pair; chunks are 1024 wide.
// chunks per m-tile = (m>>3)+1; single-chunk tiles store, multi-chunk
// tiles atomicAdd into the zeroed d_out.
// ---------------------------------------------------------------------------
__global__ __launch_bounds__(256) void pv_gemm(
    const unsigned short* __restrict__ Sb, const unsigned short* __restrict__ Vt,
    float* __restrict__ out)
{
    __shared__ __align__(16) unsigned short sA[128 * 32];
    __shared__ __align__(16) unsigned short sB[128 * 32];
    const int n0 = blockIdx.x * 128;    // 0..896
    const int y = blockIdx.y;           // 0..79
    int m, c;
    if (y < 8)       { m = y;               c = 0; }
    else if (y < 24) { m = 8 + (y - 8) / 2;  c = (y - 8) % 2; }
    else if (y < 48) { m = 16 + (y - 24) / 3; c = (y - 24) % 3; }
    else             { m = 24 + (y - 48) / 4; c = (y - 48) % 4; }
    const int m0 = m * 128;
    const int kstart = c * 1024;
    const int kend = min((m + 1) * 128, kstart + 1024);
    const int nchunks = (m >> 3) + 1;

    f32x4 acc[4][4];
    zero_acc(acc);
    mfma_tile_loop(Sb + m0 * SEQ + kstart, SEQ, Vt + n0 * SEQ + kstart, SEQ,
                   kend - kstart, sA, sB, acc);

    const int lane = threadIdx.x & 63, wave = threadIdx.x >> 6;
    const int lr = lane & 15, quad = lane >> 4;
    const int wm = (wave >> 1) * 64, wn = (wave & 1) * 64;
    #pragma unroll
    for (int i = 0; i < 4; ++i) {
        const int rbase = m0 + wm + 16 * i + quad * 4;
        #pragma unroll
        for (int j = 0; j < 4; ++j) {
            const int col = n0 + wn + 16 * j + lr;
            if (nchunks == 1) {
                #pragma unroll
                for (int r = 0; r < 4; ++r)
                    out[(rbase + r) * KDIM + col] = acc[i][j][r];
            } else {
                #pragma unroll
                for (int r = 0; r < 4; ++r)
                    atomicAdd(&out[(rbase + r) * KDIM + col], acc[i][j][r]);
            }
        }
    }
}

// ---------------------------------------------------------------------------
extern "C" void kernel_launch(void* const* d_in, const int* in_sizes, int n_in,
                              void* d_out, int out_size, void* d_ws, size_t ws_size,
                              hipStream_t stream) {
    const float* x = (const float*)d_in[0];   // [4096][1024]
    const float* W = (const float*)d_in[1];   // [1024][3072]
    float* out = (float*)d_out;               // [4096][1024]
    char* ws = (char*)d_ws;

    // workspace layout (bytes)
    unsigned short* Xb = (unsigned short*)(ws);                     //  8 MiB
    unsigned short* Wt = (unsigned short*)(ws + 8388608);           //  6 MiB
    unsigned short* Qb = (unsigned short*)(ws + 14680064);          //  8 MiB
    unsigned short* Kb = (unsigned short*)(ws + 23068672);          //  8 MiB
    unsigned short* Vt = (unsigned short*)(ws + 31457280);          //  8 MiB
    unsigned short* Sb = (unsigned short*)(ws + 39845888);          // 32 MiB  (ends 73400320)

    convert_x  <<<SEQ * KDIM / (256 * 4), 256, 0, stream>>>(x, Xb);
    transpose_W<<<dim3(NQKV / 32, KDIM / 32), 256, 0, stream>>>(W, Wt);
    zero_out   <<<SEQ * KDIM / (256 * 4), 256, 0, stream>>>((float4*)out);
    qvk_gemm   <<<dim3(NQKV / 128, SEQ / 128), 256, 0, stream>>>(Xb, Wt, Qb, Kb, Vt);
    score_gemm <<<(SEQ / 128) * (SEQ / 128 + 1) / 2, 256, 0, stream>>>(Qb, Kb, Sb);
    softmax_rows<<<SEQ, 256, 0, stream>>>(Sb);
    pv_gemm    <<<dim3(KDIM / 128, 80), 256, 0, stream>>>(Sb, Vt, out);
}

// Round 3
// 206.094 us; speedup vs baseline: 1.3321x; 1.1863x over previous
//
#include <hip/hip_runtime.h>

#define SEQ 4096
#define KDIM 1024
#define NQKV 3072
#define BK 32

typedef __bf16 bf16x8 __attribute__((ext_vector_type(8)));
typedef float  f32x4  __attribute__((ext_vector_type(4)));

__device__ __forceinline__ unsigned short f2b(float f) {
    unsigned int u = __float_as_uint(f);
    u += 0x7FFFu + ((u >> 16) & 1u);   // round-to-nearest-even
    return (unsigned short)(u >> 16);
}
__device__ __forceinline__ float b2f(unsigned short h) {
    return __uint_as_float(((unsigned int)h) << 16);
}

__device__ __forceinline__ void gld_lds16(const unsigned short* g, unsigned short* l) {
    __builtin_amdgcn_global_load_lds(
        (const __attribute__((address_space(1))) void*)g,
        (__attribute__((address_space(3))) void*)l, 16, 0, 0);
}

// ---------------------------------------------------------------------------
// Double-buffered 128x128x32 MFMA tile loop. 4 waves (2x2), 64x64 per wave.
// A: Ag[m][k] row-major (pre-offset), lda elems. B: Bg[n][k] (pre-offset), ldb.
// lds = 32 KiB: buf0 A(8K) B(8K), buf1 A(8K) B(8K).
// ---------------------------------------------------------------------------
__device__ __forceinline__ void stage_tiles(
    const unsigned short* Ag, int lda, const unsigned short* Bg, int ldb,
    int k0, unsigned short* sA, unsigned short* sB, int wave, int lane)
{
    #pragma unroll
    for (int i = 0; i < 2; ++i) {
        int c = wave * 128 + i * 64 + lane;     // chunk id 0..511
        int row = c >> 2, piece = c & 3;        // 4 x 16B chunks per row
        gld_lds16(Ag + row * lda + k0 + piece * 8, sA + (wave * 2 + i) * 512);
        gld_lds16(Bg + row * ldb + k0 + piece * 8, sB + (wave * 2 + i) * 512);
    }
}

__device__ __forceinline__ void compute_tile(
    const unsigned short* sA, const unsigned short* sB, f32x4 acc[4][4],
    int wm, int wn, int lr, int quad)
{
    bf16x8 af[4], bq[4];
    #pragma unroll
    for (int i = 0; i < 4; ++i)
        af[i] = *(const bf16x8*)(sA + (wm + 16 * i + lr) * 32 + quad * 8);
    #pragma unroll
    for (int j = 0; j < 4; ++j)
        bq[j] = *(const bf16x8*)(sB + (wn + 16 * j + lr) * 32 + quad * 8);
    #pragma unroll
    for (int i = 0; i < 4; ++i)
        #pragma unroll
        for (int j = 0; j < 4; ++j)
            acc[i][j] = __builtin_amdgcn_mfma_f32_16x16x32_bf16(af[i], bq[j], acc[i][j], 0, 0, 0);
}

__device__ __forceinline__ void mfma_db(
    const unsigned short* Ag, int lda, const unsigned short* Bg, int ldb,
    int kLen, unsigned short* lds, f32x4 acc[4][4])
{
    const int tid  = threadIdx.x;
    const int wave = tid >> 6, lane = tid & 63;
    const int lr   = lane & 15, quad = lane >> 4;
    const int wm   = (wave >> 1) * 64, wn = (wave & 1) * 64;
    unsigned short* sA0 = lds;
    unsigned short* sB0 = lds + 4096;
    unsigned short* sA1 = lds + 8192;
    unsigned short* sB1 = lds + 12288;

    stage_tiles(Ag, lda, Bg, ldb, 0, sA0, sB0, wave, lane);
    int k = BK;
    #pragma unroll 1
    for (; k + BK < kLen; k += 2 * BK) {
        __syncthreads();                               // buf0 ready; buf1 free
        stage_tiles(Ag, lda, Bg, ldb, k, sA1, sB1, wave, lane);
        compute_tile(sA0, sB0, acc, wm, wn, lr, quad); // overlaps buf1 loads
        __syncthreads();                               // buf1 ready; buf0 free
        stage_tiles(Ag, lda, Bg, ldb, k + BK, sA0, sB0, wave, lane);
        compute_tile(sA1, sB1, acc, wm, wn, lr, quad);
    }
    if (k < kLen) {                                    // one stage + two computes left
        __syncthreads();
        stage_tiles(Ag, lda, Bg, ldb, k, sA1, sB1, wave, lane);
        compute_tile(sA0, sB0, acc, wm, wn, lr, quad);
        __syncthreads();
        compute_tile(sA1, sB1, acc, wm, wn, lr, quad);
    } else {                                           // one compute left
        __syncthreads();
        compute_tile(sA0, sB0, acc, wm, wn, lr, quad);
    }
}

__device__ __forceinline__ void zero_acc(f32x4 acc[4][4]) {
    const f32x4 z = {0.f, 0.f, 0.f, 0.f};
    #pragma unroll
    for (int i = 0; i < 4; ++i)
        #pragma unroll
        for (int j = 0; j < 4; ++j) acc[i][j] = z;
}

// ---------------------------------------------------------------------------
// Epilogue: wave-private LDS restage -> 16B coalesced bf16 stores.
// Row-major: each lane ends up storing 8 consecutive cols of one row.
// lw: per-wave >= 16*72 shorts (2304 B), 16B aligned. Wave-synchronous.
// ---------------------------------------------------------------------------
__device__ __forceinline__ void store_rows_bf16(
    f32x4 acc[4][4], unsigned short* Cw, int ld, unsigned short* lw, int lane)
{
    const int lr = lane & 15, quad = lane >> 4;
    #pragma unroll
    for (int i = 0; i < 4; ++i) {
        #pragma unroll
        for (int j = 0; j < 4; ++j)
            #pragma unroll
            for (int r = 0; r < 4; ++r)
                lw[(quad * 4 + r) * 72 + j * 16 + lr] = f2b(acc[i][j][r]);
        #pragma unroll
        for (int t = 0; t < 2; ++t) {
            int chunk = t * 64 + lane;          // 0..127
            int rl = chunk >> 3, c8 = chunk & 7;
            uint4 v = *(const uint4*)(lw + rl * 72 + c8 * 8);
            *(uint4*)(Cw + (16 * i + rl) * ld + c8 * 8) = v;
        }
    }
}

// Transposed (Vt[d][s]): each lane stores 8 consecutive s for one d.
// lw: per-wave >= 64*40 shorts (5120 B), 16B aligned.
__device__ __forceinline__ void store_cols_bf16(
    f32x4 acc[4][4], unsigned short* Vw, unsigned short* lw, int lane)
{
    const int lr = lane & 15, quad = lane >> 4;
    #pragma unroll
    for (int ip = 0; ip < 2; ++ip) {            // 32 s-rows per pass
        #pragma unroll
        for (int ii = 0; ii < 2; ++ii)
            #pragma unroll
            for (int j = 0; j < 4; ++j)
                #pragma unroll
                for (int r = 0; r < 4; ++r)
                    lw[(j * 16 + lr) * 40 + ii * 16 + quad * 4 + r] = f2b(acc[ip * 2 + ii][j][r]);
        #pragma unroll
        for (int t = 0; t < 4; ++t) {
            int chunk = t * 64 + lane;          // 0..255
            int col = chunk >> 2, c8 = chunk & 3;
            uint4 v = *(const uint4*)(lw + col * 40 + c8 * 8);
            *(uint4*)(Vw + col * SEQ + ip * 32 + c8 * 8) = v;
        }
    }
}

// ---------------------------------------------------------------------------
// Kernel 0: fused prep. blocks [0,4096): x->bf16; [4096,8192): zero d_out;
// [8192,11264): W transpose+convert.
// ---------------------------------------------------------------------------
__global__ __launch_bounds__(256) void prep(
    const float* __restrict__ x, unsigned short* __restrict__ Xb,
    const float* __restrict__ W, unsigned short* __restrict__ Wt,
    float4* __restrict__ out)
{
    __shared__ float tile[32][33];
    const int b = blockIdx.x, tid = threadIdx.x;
    if (b < 4096) {
        int i = (b * 256 + tid) * 4;
        float4 v = *(const float4*)(x + i);
        ushort4 o;
        o.x = f2b(v.x); o.y = f2b(v.y); o.z = f2b(v.z); o.w = f2b(v.w);
        *(ushort4*)(Xb + i) = o;
    } else if (b < 8192) {
        const float4 z = {0.f, 0.f, 0.f, 0.f};
        out[(b - 4096) * 256 + tid] = z;
    } else {
        const int bb = b - 8192;
        const int n0 = (bb % 96) * 32, k0 = (bb / 96) * 32;
        const int c = tid & 31, r0 = tid >> 5;
        #pragma unroll
        for (int r = r0; r < 32; r += 8)
            tile[r][c] = W[(k0 + r) * NQKV + n0 + c];
        __syncthreads();
        #pragma unroll
        for (int r = r0; r < 32; r += 8)
            Wt[(n0 + r) * KDIM + k0 + c] = f2b(tile[c][r]);
    }
}

// ---------------------------------------------------------------------------
// Kernel 1: qvk = Xb @ Wt^T -> Q rows, K rows, V transposed (Vt[d][s])
// ---------------------------------------------------------------------------
__global__ __launch_bounds__(256) void qvk_gemm(
    const unsigned short* __restrict__ Xb, const unsigned short* __restrict__ Wt,
    unsigned short* __restrict__ Qb, unsigned short* __restrict__ Kb,
    unsigned short* __restrict__ Vt)
{
    __shared__ __align__(16) unsigned short lds[16384];   // 32 KiB
    const int m0 = blockIdx.y * 128;
    const int n0 = blockIdx.x * 128;
    f32x4 acc[4][4];
    zero_acc(acc);
    mfma_db(Xb + m0 * KDIM, KDIM, Wt + n0 * KDIM, KDIM, KDIM, lds, acc);
    __syncthreads();                                      // free LDS for restage

    const int lane = threadIdx.x & 63, wave = threadIdx.x >> 6;
    const int wm = (wave >> 1) * 64, wn = (wave & 1) * 64;
    unsigned short* lw = lds + wave * 2560;
    const int region = n0 >> 10;
    const int nloc = n0 & 1023;
    if (region == 0)
        store_rows_bf16(acc, Qb + (m0 + wm) * KDIM + nloc + wn, KDIM, lw, lane);
    else if (region == 2)
        store_rows_bf16(acc, Kb + (m0 + wm) * KDIM + nloc + wn, KDIM, lw, lane);
    else
        store_cols_bf16(acc, Vt + (nloc + wn) * SEQ + m0 + wm, lw, lane);
}

// ---------------------------------------------------------------------------
// Kernel 2: S = (Q @ K^T)/32, causal; lower-triangular blocks only.
// ---------------------------------------------------------------------------
__global__ __launch_bounds__(256) void score_gemm(
    const unsigned short* __restrict__ Qb, const unsigned short* __restrict__ Kb,
    unsigned short* __restrict__ Sb)
{
    __shared__ __align__(16) unsigned short lds[16384];
    const int b = blockIdx.x;
    int bm = (int)((sqrtf(8.f * (float)b + 1.f) - 1.f) * 0.5f);
    while ((bm + 1) * (bm + 2) / 2 <= b) ++bm;
    while (bm * (bm + 1) / 2 > b) --bm;
    const int bn = b - bm * (bm + 1) / 2;
    const int m0 = bm * 128, n0 = bn * 128;

    f32x4 acc[4][4];
    zero_acc(acc);
    mfma_db(Qb + m0 * KDIM, KDIM, Kb + n0 * KDIM, KDIM, KDIM, lds, acc);

    const int lane = threadIdx.x & 63, wave = threadIdx.x >> 6;
    const int lr = lane & 15, quad = lane >> 4;
    const int wm = (wave >> 1) * 64, wn = (wave & 1) * 64;
    // scale + (diag-block) causal mask, in registers
    #pragma unroll
    for (int i = 0; i < 4; ++i)
        #pragma unroll
        for (int j = 0; j < 4; ++j)
            #pragma unroll
            for (int r = 0; r < 4; ++r) {
                float v = acc[i][j][r] * 0.03125f;
                if (bm == bn) {
                    int row = wm + 16 * i + quad * 4 + r;
                    int col = wn + 16 * j + lr;
                    if (col > row) v = -1e30f;
                }
                acc[i][j][r] = v;
            }
    __syncthreads();
    store_rows_bf16(acc, Sb + (m0 + wm) * SEQ + n0 + wn, SEQ, lds + wave * 2560, lane);
}

// ---------------------------------------------------------------------------
// Kernel 3: row softmax on Sb, register-resident, vectorized.
// Row m covers [0, jend) with jend = 128-aligned end (uniform per 128-tile);
// each active thread owns 16 contiguous elements.
// ---------------------------------------------------------------------------
__global__ __launch_bounds__(256) void softmax_rows(unsigned short* __restrict__ Sb) {
    const int m = blockIdx.x;
    const int jend = ((m >> 7) + 1) << 7;
    const int tid = threadIdx.x;
    const int nact = jend >> 4;
    const bool act = tid < nact;
    __shared__ float red[256];

    unsigned short* p = Sb + m * SEQ + tid * 16;
    float v[16];
    float lmax = -3.0e38f;
    if (act) {
        unsigned int u[8];
        *(uint4*)&u[0] = *(const uint4*)p;
        *(uint4*)&u[4] = *(const uint4*)(p + 8);
        #pragma unroll
        for (int k = 0; k < 8; ++k) {
            v[2 * k]     = b2f((unsigned short)(u[k] & 0xFFFFu));
            v[2 * k + 1] = b2f((unsigned short)(u[k] >> 16));
        }
        #pragma unroll
        for (int k = 0; k < 16; ++k) lmax = fmaxf(lmax, v[k]);
    }
    red[tid] = lmax;
    __syncthreads();
    for (int s = 128; s > 0; s >>= 1) {
        if (tid < s) red[tid] = fmaxf(red[tid], red[tid + s]);
        __syncthreads();
    }
    const float rmax = red[0];
    __syncthreads();

    float lsum = 0.f;
    if (act) {
        #pragma unroll
        for (int k = 0; k < 16; ++k) {
            v[k] = __expf(v[k] - rmax);
            lsum += v[k];
        }
    }
    red[tid] = lsum;
    __syncthreads();
    for (int s = 128; s > 0; s >>= 1) {
        if (tid < s) red[tid] += red[tid + s];
        __syncthreads();
    }
    const float inv = 1.0f / red[0];
    if (act) {
        unsigned int o[8];
        #pragma unroll
        for (int k = 0; k < 8; ++k)
            o[k] = (unsigned int)f2b(v[2 * k] * inv)
                 | ((unsigned int)f2b(v[2 * k + 1] * inv) << 16);
        *(uint4*)p = *(uint4*)&o[0];
        *(uint4*)(p + 8) = *(uint4*)&o[4];
    }
}

// ---------------------------------------------------------------------------
// Kernel 4: out = P @ V, split-K (1024-wide chunks) over causal extent.
// ---------------------------------------------------------------------------
__global__ __launch_bounds__(256) void pv_gemm(
    const unsigned short* __restrict__ Sb, const unsigned short* __restrict__ Vt,
    float* __restrict__ out)
{
    __shared__ __align__(16) unsigned short lds[16384];
    const int n0 = blockIdx.x * 128;
    const int y = blockIdx.y;               // 0..79
    int m, c;
    if (y < 8)       { m = y;                 c = 0; }
    else if (y < 24) { m = 8 + (y - 8) / 2;   c = (y - 8) % 2; }
    else if (y < 48) { m = 16 + (y - 24) / 3; c = (y - 24) % 3; }
    else             { m = 24 + (y - 48) / 4; c = (y - 48) % 4; }
    const int m0 = m * 128;
    const int kstart = c * 1024;
    const int kend = min((m + 1) * 128, kstart + 1024);
    const int nchunks = (m >> 3) + 1;

    f32x4 acc[4][4];
    zero_acc(acc);
    mfma_db(Sb + m0 * SEQ + kstart, SEQ, Vt + n0 * SEQ + kstart, SEQ,
            kend - kstart, lds, acc);

    const int lane = threadIdx.x & 63, wave = threadIdx.x >> 6;
    const int lr = lane & 15, quad = lane >> 4;
    const int wm = (wave >> 1) * 64, wn = (wave & 1) * 64;
    #pragma unroll
    for (int i = 0; i < 4; ++i) {
        const int rbase = m0 + wm + 16 * i + quad * 4;
        #pragma unroll
        for (int j = 0; j < 4; ++j) {
            const int col = n0 + wn + 16 * j + lr;
            if (nchunks == 1) {
                #pragma unroll
                for (int r = 0; r < 4; ++r)
                    out[(rbase + r) * KDIM + col] = acc[i][j][r];
            } else {
                #pragma unroll
                for (int r = 0; r < 4; ++r)
                    atomicAdd(&out[(rbase + r) * KDIM + col], acc[i][j][r]);
            }
        }
    }
}

// ---------------------------------------------------------------------------
extern "C" void kernel_launch(void* const* d_in, const int* in_sizes, int n_in,
                              void* d_out, int out_size, void* d_ws, size_t ws_size,
                              hipStream_t stream) {
    const float* x = (const float*)d_in[0];   // [4096][1024]
    const float* W = (const float*)d_in[1];   // [1024][3072]
    float* out = (float*)d_out;               // [4096][1024]
    char* ws = (char*)d_ws;

    unsigned short* Xb = (unsigned short*)(ws);                     //  8 MiB
    unsigned short* Wt = (unsigned short*)(ws + 8388608);           //  6 MiB
    unsigned short* Qb = (unsigned short*)(ws + 14680064);          //  8 MiB
    unsigned short* Kb = (unsigned short*)(ws + 23068672);          //  8 MiB
    unsigned short* Vt = (unsigned short*)(ws + 31457280);          //  8 MiB
    unsigned short* Sb = (unsigned short*)(ws + 39845888);          // 32 MiB

    prep        <<<11264, 256, 0, stream>>>(x, Xb, W, Wt, (float4*)out);
    qvk_gemm    <<<dim3(NQKV / 128, SEQ / 128), 256, 0, stream>>>(Xb, Wt, Qb, Kb, Vt);
    score_gemm  <<<(SEQ / 128) * (SEQ / 128 + 1) / 2, 256, 0, stream>>>(Qb, Kb, Sb);
    softmax_rows<<<SEQ, 256, 0, stream>>>(Sb);
    pv_gemm     <<<dim3(KDIM / 128, 80), 256, 0, stream>>>(Sb, Vt, out);
}

// Round 4
// 200.951 us; speedup vs baseline: 1.3662x; 1.0256x over previous
//
#include <hip/hip_runtime.h>

#define SEQ 4096
#define KDIM 1024
#define NQKV 3072
#define BK 32

typedef __bf16 bf16x8 __attribute__((ext_vector_type(8)));
typedef float  f32x4  __attribute__((ext_vector_type(4)));

__device__ __forceinline__ unsigned short f2b(float f) {
    unsigned int u = __float_as_uint(f);
    u += 0x7FFFu + ((u >> 16) & 1u);   // round-to-nearest-even
    return (unsigned short)(u >> 16);
}
__device__ __forceinline__ float b2f(unsigned short h) {
    return __uint_as_float(((unsigned int)h) << 16);
}

__device__ __forceinline__ void gld_lds16(const unsigned short* g, unsigned short* l) {
    __builtin_amdgcn_global_load_lds(
        (const __attribute__((address_space(1))) void*)g,
        (__attribute__((address_space(3))) void*)l, 16, 0, 0);
}

// ---------------------------------------------------------------------------
// Double-buffered 128x128x32 MFMA tile loop, XOR-swizzled LDS.
// Tile row = 32 shorts (64 B) = 4 x 16B pieces. Piece p of row r lives in
// LDS slot (p ^ ((r>>1)&3)) -> 16-lane b128 fragment reads are 2-way (free)
// instead of 8-way conflicted.
// ---------------------------------------------------------------------------
__device__ __forceinline__ void stage_tiles(
    const unsigned short* Ag, int lda, const unsigned short* Bg, int ldb,
    int k0, unsigned short* sA, unsigned short* sB, int wave, int lane)
{
    #pragma unroll
    for (int i = 0; i < 2; ++i) {
        int c = wave * 128 + i * 64 + lane;        // chunk id 0..511
        int row = c >> 2, slot = c & 3;
        int p = slot ^ ((row >> 1) & 3);           // global piece for this slot
        gld_lds16(Ag + row * lda + k0 + p * 8, sA + (wave * 2 + i) * 512);
        gld_lds16(Bg + row * ldb + k0 + p * 8, sB + (wave * 2 + i) * 512);
    }
}

__device__ __forceinline__ const unsigned short* frag_addr(
    const unsigned short* s, int row, int quad)
{
    return s + row * 32 + (quad ^ ((row >> 1) & 3)) * 8;
}

__device__ __forceinline__ void compute_tile(
    const unsigned short* sA, const unsigned short* sB, f32x4 acc[4][4],
    int wm, int wn, int lr, int quad)
{
    bf16x8 af[4], bq[4];
    #pragma unroll
    for (int i = 0; i < 4; ++i)
        af[i] = *(const bf16x8*)frag_addr(sA, wm + 16 * i + lr, quad);
    #pragma unroll
    for (int j = 0; j < 4; ++j)
        bq[j] = *(const bf16x8*)frag_addr(sB, wn + 16 * j + lr, quad);
    #pragma unroll
    for (int i = 0; i < 4; ++i)
        #pragma unroll
        for (int j = 0; j < 4; ++j)
            acc[i][j] = __builtin_amdgcn_mfma_f32_16x16x32_bf16(af[i], bq[j], acc[i][j], 0, 0, 0);
}

__device__ __forceinline__ void mfma_db(
    const unsigned short* Ag, int lda, const unsigned short* Bg, int ldb,
    int kLen, unsigned short* lds, f32x4 acc[4][4])
{
    const int tid  = threadIdx.x;
    const int wave = tid >> 6, lane = tid & 63;
    const int lr   = lane & 15, quad = lane >> 4;
    const int wm   = (wave >> 1) * 64, wn = (wave & 1) * 64;
    unsigned short* sA0 = lds;
    unsigned short* sB0 = lds + 4096;
    unsigned short* sA1 = lds + 8192;
    unsigned short* sB1 = lds + 12288;

    stage_tiles(Ag, lda, Bg, ldb, 0, sA0, sB0, wave, lane);
    int k = BK;
    #pragma unroll 1
    for (; k + BK < kLen; k += 2 * BK) {
        __syncthreads();
        stage_tiles(Ag, lda, Bg, ldb, k, sA1, sB1, wave, lane);
        compute_tile(sA0, sB0, acc, wm, wn, lr, quad);
        __syncthreads();
        stage_tiles(Ag, lda, Bg, ldb, k + BK, sA0, sB0, wave, lane);
        compute_tile(sA1, sB1, acc, wm, wn, lr, quad);
    }
    if (k < kLen) {
        __syncthreads();
        stage_tiles(Ag, lda, Bg, ldb, k, sA1, sB1, wave, lane);
        compute_tile(sA0, sB0, acc, wm, wn, lr, quad);
        __syncthreads();
        compute_tile(sA1, sB1, acc, wm, wn, lr, quad);
    } else {
        __syncthreads();
        compute_tile(sA0, sB0, acc, wm, wn, lr, quad);
    }
}

__device__ __forceinline__ void zero_acc(f32x4 acc[4][4]) {
    const f32x4 z = {0.f, 0.f, 0.f, 0.f};
    #pragma unroll
    for (int i = 0; i < 4; ++i)
        #pragma unroll
        for (int j = 0; j < 4; ++j) acc[i][j] = z;
}

// ---------------------------------------------------------------------------
// Epilogue: wave-private LDS restage -> 16B coalesced bf16 stores.
// ---------------------------------------------------------------------------
__device__ __forceinline__ void store_rows_bf16(
    f32x4 acc[4][4], unsigned short* Cw, int ld, unsigned short* lw, int lane)
{
    const int lr = lane & 15, quad = lane >> 4;
    #pragma unroll
    for (int i = 0; i < 4; ++i) {
        #pragma unroll
        for (int j = 0; j < 4; ++j)
            #pragma unroll
            for (int r = 0; r < 4; ++r)
                lw[(quad * 4 + r) * 72 + j * 16 + lr] = f2b(acc[i][j][r]);
        #pragma unroll
        for (int t = 0; t < 2; ++t) {
            int chunk = t * 64 + lane;          // 0..127
            int rl = chunk >> 3, c8 = chunk & 7;
            uint4 v = *(const uint4*)(lw + rl * 72 + c8 * 8);
            *(uint4*)(Cw + (16 * i + rl) * ld + c8 * 8) = v;
        }
    }
}

// Transposed (Vt[d][s]): each lane stores 8 consecutive s for one d.
__device__ __forceinline__ void store_cols_bf16(
    f32x4 acc[4][4], unsigned short* Vw, unsigned short* lw, int lane)
{
    const int lr = lane & 15, quad = lane >> 4;
    #pragma unroll
    for (int ip = 0; ip < 2; ++ip) {            // 32 s-rows per pass
        #pragma unroll
        for (int ii = 0; ii < 2; ++ii)
            #pragma unroll
            for (int j = 0; j < 4; ++j)
                #pragma unroll
                for (int r = 0; r < 4; ++r)
                    lw[(j * 16 + lr) * 40 + ii * 16 + quad * 4 + r] = f2b(acc[ip * 2 + ii][j][r]);
        #pragma unroll
        for (int t = 0; t < 4; ++t) {
            int chunk = t * 64 + lane;          // 0..255
            int col = chunk >> 2, c8 = chunk & 3;
            uint4 v = *(const uint4*)(lw + col * 40 + c8 * 8);
            *(uint4*)(Vw + col * SEQ + ip * 32 + c8 * 8) = v;
        }
    }
}

// ---------------------------------------------------------------------------
// Kernel 0: fused prep. [0,4096): x->bf16; [4096,8192): zero d_out;
// [8192,11264): W transpose; block 11264: zero l[4096].
// ---------------------------------------------------------------------------
__global__ __launch_bounds__(256) void prep(
    const float* __restrict__ x, unsigned short* __restrict__ Xb,
    const float* __restrict__ W, unsigned short* __restrict__ Wt,
    float4* __restrict__ out, float4* __restrict__ lrow)
{
    __shared__ float tile[32][33];
    const int b = blockIdx.x, tid = threadIdx.x;
    if (b < 4096) {
        int i = (b * 256 + tid) * 4;
        float4 v = *(const float4*)(x + i);
        ushort4 o;
        o.x = f2b(v.x); o.y = f2b(v.y); o.z = f2b(v.z); o.w = f2b(v.w);
        *(ushort4*)(Xb + i) = o;
    } else if (b < 8192) {
        const float4 z = {0.f, 0.f, 0.f, 0.f};
        out[(b - 4096) * 256 + tid] = z;
    } else if (b < 11264) {
        const int bb = b - 8192;
        const int n0 = (bb % 96) * 32, k0 = (bb / 96) * 32;
        const int c = tid & 31, r0 = tid >> 5;
        #pragma unroll
        for (int r = r0; r < 32; r += 8)
            tile[r][c] = W[(k0 + r) * NQKV + n0 + c];
        __syncthreads();
        #pragma unroll
        for (int r = r0; r < 32; r += 8)
            Wt[(n0 + r) * KDIM + k0 + c] = f2b(tile[c][r]);
    } else {
        const float4 z = {0.f, 0.f, 0.f, 0.f};
        #pragma unroll
        for (int k = 0; k < 4; ++k) lrow[tid * 4 + k] = z;
    }
}

// ---------------------------------------------------------------------------
// Kernel 1: qvk = Xb @ Wt^T -> Q rows, K rows, V transposed (Vt[d][s])
// ---------------------------------------------------------------------------
__global__ __launch_bounds__(256) void qvk_gemm(
    const unsigned short* __restrict__ Xb, const unsigned short* __restrict__ Wt,
    unsigned short* __restrict__ Qb, unsigned short* __restrict__ Kb,
    unsigned short* __restrict__ Vt)
{
    __shared__ __align__(16) unsigned short lds[16384];   // 32 KiB
    const int m0 = blockIdx.y * 128;
    const int n0 = blockIdx.x * 128;
    f32x4 acc[4][4];
    zero_acc(acc);
    mfma_db(Xb + m0 * KDIM, KDIM, Wt + n0 * KDIM, KDIM, KDIM, lds, acc);
    __syncthreads();

    const int lane = threadIdx.x & 63, wave = threadIdx.x >> 6;
    const int wm = (wave >> 1) * 64, wn = (wave & 1) * 64;
    unsigned short* lw = lds + wave * 2560;
    const int region = n0 >> 10;
    const int nloc = n0 & 1023;
    if (region == 0)
        store_rows_bf16(acc, Qb + (m0 + wm) * KDIM + nloc + wn, KDIM, lw, lane);
    else if (region == 2)
        store_rows_bf16(acc, Kb + (m0 + wm) * KDIM + nloc + wn, KDIM, lw, lane);
    else
        store_cols_bf16(acc, Vt + (nloc + wn) * SEQ + m0 + wm, lw, lane);
}

// ---------------------------------------------------------------------------
// Kernel 2: fused score+exp. P = exp((Q@K^T)/32) causal (no max-sub: |s|<=16
// by Cauchy-Schwarz, exp is fp32-safe). Row sums atomicAdd'd into lrow[];
// P written bf16 to Sb (lower-tri blocks only). Softmax normalization is
// folded into pv via 1/lrow.
// ---------------------------------------------------------------------------
__global__ __launch_bounds__(256) void score_exp_gemm(
    const unsigned short* __restrict__ Qb, const unsigned short* __restrict__ Kb,
    unsigned short* __restrict__ Sb, float* __restrict__ lrow)
{
    __shared__ __align__(16) unsigned short lds[16384];
    const int b = blockIdx.x;
    int bm = (int)((sqrtf(8.f * (float)b + 1.f) - 1.f) * 0.5f);
    while ((bm + 1) * (bm + 2) / 2 <= b) ++bm;
    while (bm * (bm + 1) / 2 > b) --bm;
    const int bn = b - bm * (bm + 1) / 2;
    const int m0 = bm * 128, n0 = bn * 128;

    f32x4 acc[4][4];
    zero_acc(acc);
    mfma_db(Qb + m0 * KDIM, KDIM, Kb + n0 * KDIM, KDIM, KDIM, lds, acc);

    const int lane = threadIdx.x & 63, wave = threadIdx.x >> 6;
    const int lr = lane & 15, quad = lane >> 4;
    const int wm = (wave >> 1) * 64, wn = (wave & 1) * 64;
    // P = exp(scale * s), causal-masked on diagonal blocks
    #pragma unroll
    for (int i = 0; i < 4; ++i)
        #pragma unroll
        for (int j = 0; j < 4; ++j)
            #pragma unroll
            for (int r = 0; r < 4; ++r) {
                float v = __expf(acc[i][j][r] * 0.03125f);
                if (bm == bn) {
                    int row = wm + 16 * i + quad * 4 + r;
                    int col = wn + 16 * j + lr;
                    if (col > row) v = 0.f;
                }
                acc[i][j][r] = v;
            }
    // per-row sums over this wave's 64 cols -> atomicAdd into lrow
    #pragma unroll
    for (int i = 0; i < 4; ++i)
        #pragma unroll
        for (int r = 0; r < 4; ++r) {
            float s = acc[i][0][r] + acc[i][1][r] + acc[i][2][r] + acc[i][3][r];
            s += __shfl_xor(s, 1, 16);
            s += __shfl_xor(s, 2, 16);
            s += __shfl_xor(s, 4, 16);
            s += __shfl_xor(s, 8, 16);
            if (lr == 0)
                atomicAdd(&lrow[m0 + wm + 16 * i + quad * 4 + r], s);
        }
    __syncthreads();
    store_rows_bf16(acc, Sb + (m0 + wm) * SEQ + n0 + wn, SEQ, lds + wave * 2560, lane);
}

// ---------------------------------------------------------------------------
// Kernel 3: out = (P @ V) / l, split-K (1024-wide chunks) over causal extent.
// ---------------------------------------------------------------------------
__global__ __launch_bounds__(256) void pv_gemm(
    const unsigned short* __restrict__ Sb, const unsigned short* __restrict__ Vt,
    const float* __restrict__ lrow, float* __restrict__ out)
{
    __shared__ __align__(16) unsigned short lds[16384];
    const int n0 = blockIdx.x * 128;
    const int y = blockIdx.y;               // 0..79
    int m, c;
    if (y < 8)       { m = y;                 c = 0; }
    else if (y < 24) { m = 8 + (y - 8) / 2;   c = (y - 8) % 2; }
    else if (y < 48) { m = 16 + (y - 24) / 3; c = (y - 24) % 3; }
    else             { m = 24 + (y - 48) / 4; c = (y - 48) % 4; }
    const int m0 = m * 128;
    const int kstart = c * 1024;
    const int kend = min((m + 1) * 128, kstart + 1024);
    const int nchunks = (m >> 3) + 1;

    f32x4 acc[4][4];
    zero_acc(acc);
    mfma_db(Sb + m0 * SEQ + kstart, SEQ, Vt + n0 * SEQ + kstart, SEQ,
            kend - kstart, lds, acc);

    const int lane = threadIdx.x & 63, wave = threadIdx.x >> 6;
    const int lr = lane & 15, quad = lane >> 4;
    const int wm = (wave >> 1) * 64, wn = (wave & 1) * 64;
    #pragma unroll
    for (int i = 0; i < 4; ++i) {
        const int rbase = m0 + wm + 16 * i + quad * 4;
        const float4 l4 = *(const float4*)(lrow + rbase);
        float inv[4] = {1.0f / l4.x, 1.0f / l4.y, 1.0f / l4.z, 1.0f / l4.w};
        #pragma unroll
        for (int j = 0; j < 4; ++j) {
            const int col = n0 + wn + 16 * j + lr;
            if (nchunks == 1) {
                #pragma unroll
                for (int r = 0; r < 4; ++r)
                    out[(rbase + r) * KDIM + col] = acc[i][j][r] * inv[r];
            } else {
                #pragma unroll
                for (int r = 0; r < 4; ++r)
                    atomicAdd(&out[(rbase + r) * KDIM + col], acc[i][j][r] * inv[r]);
            }
        }
    }
}

// ---------------------------------------------------------------------------
extern "C" void kernel_launch(void* const* d_in, const int* in_sizes, int n_in,
                              void* d_out, int out_size, void* d_ws, size_t ws_size,
                              hipStream_t stream) {
    const float* x = (const float*)d_in[0];   // [4096][1024]
    const float* W = (const float*)d_in[1];   // [1024][3072]
    float* out = (float*)d_out;               // [4096][1024]
    char* ws = (char*)d_ws;

    unsigned short* Xb = (unsigned short*)(ws);                     //  8 MiB
    unsigned short* Wt = (unsigned short*)(ws + 8388608);           //  6 MiB
    unsigned short* Qb = (unsigned short*)(ws + 14680064);          //  8 MiB
    unsigned short* Kb = (unsigned short*)(ws + 23068672);          //  8 MiB
    unsigned short* Vt = (unsigned short*)(ws + 31457280);          //  8 MiB
    unsigned short* Sb = (unsigned short*)(ws + 39845888);          // 32 MiB
    float*        lrow = (float*)(ws + 73400320);                   // 16 KiB

    prep          <<<11265, 256, 0, stream>>>(x, Xb, W, Wt, (float4*)out, (float4*)lrow);
    qvk_gemm      <<<dim3(NQKV / 128, SEQ / 128), 256, 0, stream>>>(Xb, Wt, Qb, Kb, Vt);
    score_exp_gemm<<<(SEQ / 128) * (SEQ / 128 + 1) / 2, 256, 0, stream>>>(Qb, Kb, Sb, lrow);
    pv_gemm       <<<dim3(KDIM / 128, 80), 256, 0, stream>>>(Sb, Vt, lrow, out);
}